// Round 9
// baseline (380.692 us; speedup 1.0000x reference)
//
#include <hip/hip_runtime.h>
#include <hip/hip_cooperative_groups.h>

namespace cg = cooperative_groups;

#define N_NODES 50000
#define N_EDGES 800000
#define D 128
#define HP 256               // partitions for hist/fill (= gridDim)
#define EPB (N_EDGES / HP)   // 3125 edges per partition
#define NW (N_NODES / 2)     // 25000 packed u32 words (2 nodes/word)
#define RB 196               // reduce/scan blocks: 128 words (256 nodes) each
#define NTHREADS 1024
#define NBLOCKS 256
#define TOTTHREADS (NBLOCKS * NTHREADS)

typedef __attribute__((ext_vector_type(8))) short short8;   // 8 bf16
typedef __attribute__((ext_vector_type(4))) float f32x4;

__device__ __forceinline__ unsigned short f2bf(float f) {
    unsigned u = __float_as_uint(f);
    return (unsigned short)((u + 0x7FFFu + ((u >> 16) & 1u)) >> 16);  // RNE
}
__device__ __forceinline__ float bf2f(unsigned short h) {
    return __uint_as_float((unsigned)h << 16);
}

struct KArgs {
    const int2* el2;
    unsigned int* partials;      // [HP][NW] u32: per-partition packed u8 counts
    unsigned char* brel;         // [HP][N] u8: cross-partition exclusive prefix
    int* deg_in;
    int* deg_out;
    int* blk_sum;                // [RB]
    int* row_start;              // [N]
    const float4* x4;
    uint4* xst;                  // [4][N][32] bf16, feature-tiled
    unsigned short* srcs;        // [E] u16
    const float* W;
    const float* bias;
    unsigned short* ut;          // [4][N][32] bf16 (aliases brel lifetime-disjoint)
    float* out;
};

// One cooperative kernel, 6 phases, 5 grid syncs. 100KB LDS reused per phase.
__global__ __launch_bounds__(NTHREADS) void k_mega(KArgs A) {
    __shared__ __align__(16) unsigned char lds_raw[100352];
    cg::grid_group grid = cg::this_grid();
    const int b = blockIdx.x;
    const int t = threadIdx.x;

    // ---------- P1: per-partition degree histograms (LDS u8-packed) ----------
    {
        unsigned int* h = (unsigned int*)lds_raw;
        uint4* h4 = (uint4*)lds_raw;
        for (int i = t; i < NW / 4; i += NTHREADS) h4[i] = make_uint4(0, 0, 0, 0);
        __syncthreads();
        const int2* p = A.el2 + b * EPB;
        for (int i = t; i < EPB; i += NTHREADS) {
            int2 st = p[i];
            atomicAdd(&h[st.x >> 1], 1u << ((st.x & 1) * 16));    // in-deg byte
            atomicAdd(&h[st.y >> 1], 256u << ((st.y & 1) * 16));  // out-deg byte
        }
        __syncthreads();
        uint4* dst = (uint4*)(A.partials + (size_t)b * NW);
        for (int i = t; i < NW / 4; i += NTHREADS) dst[i] = h4[i];
    }
    grid.sync();

    // ---------- P2: degree totals + brel prefixes + 256-node block sums ----------
    // so accumulates out-counts: out[2w] in so[15:0], out[2w+1] in so[31:16].
    if (b < RB) {
        int w = b * 128 + (t & 127);
        bool act = (t < 128) && (w < NW);
        unsigned int si = 0, so = 0;
        if (act) {
            for (int p = 0; p < HP; ++p) {
                unsigned pre = (so & 0xFFu) | (((so >> 16) & 0xFFu) << 8);
                ((unsigned short*)(A.brel + (size_t)p * N_NODES))[w] = (unsigned short)pre;
                unsigned int v = A.partials[p * NW + w];
                si += v & 0x00FF00FFu;
                so += (v >> 8) & 0x00FF00FFu;
            }
            *(int2*)&A.deg_in[2 * w]  = make_int2(si & 0xFFFF, si >> 16);
            *(int2*)&A.deg_out[2 * w] = make_int2(so & 0xFFFF, so >> 16);
        }
        int* sr = (int*)lds_raw;
        sr[t] = act ? (int)((so & 0xFFFFu) + (so >> 16)) : 0;
        __syncthreads();
        for (int s = 512; s > 0; s >>= 1) {
            if (t < s) sr[t] += sr[t + s];
            __syncthreads();
        }
        if (t == 0) A.blk_sum[b] = sr[0];
    }
    grid.sync();

    // ---------- P3: row_start (blocks < RB) then prescale (all blocks) ----------
    if (b < RB) {
        __shared__ int s_pref;
        if (t == 0) {
            int s = 0;
            for (int i = 0; i < b; ++i) s += A.blk_sum[i];
            s_pref = s;
        }
        int w = b * 128 + (t & 127);
        bool act = (t < 128) && (w < NW);
        int v0 = 0, v1 = 0;
        if (act) { int2 d2 = *(const int2*)&A.deg_out[2 * w]; v0 = d2.x; v1 = d2.y; }
        int pair = v0 + v1;
        int* sc = (int*)lds_raw;
        sc[t] = (t < 128) ? pair : 0;
        __syncthreads();
        for (int off = 1; off < 128; off <<= 1) {
            int aa = (t >= off && t < 128) ? sc[t - off] : 0;
            __syncthreads();
            if (t < 128) sc[t] += aa;
            __syncthreads();
        }
        if (act) {
            int base = s_pref + sc[t] - pair;
            *(int2*)&A.row_start[2 * w] = make_int2(base, base + v0);
        }
    }
    // prescale: xst[f][n][32] = bf16(rsqrt(deg_in+1) * x[n][f*32..+32])
    for (int g = b * NTHREADS + t; g < N_NODES * 16; g += TOTTHREADS) {
        int n = g >> 4, part = g & 15;
        int f = part >> 2, off = part & 3;
        float rs = rsqrtf((float)(A.deg_in[n] + 1));
        float4 a = A.x4[g * 2], c = A.x4[g * 2 + 1];
        uint4 o;
        o.x = f2bf(rs * a.x) | ((unsigned)f2bf(rs * a.y) << 16);
        o.y = f2bf(rs * a.z) | ((unsigned)f2bf(rs * a.w) << 16);
        o.z = f2bf(rs * c.x) | ((unsigned)f2bf(rs * c.y) << 16);
        o.w = f2bf(rs * c.z) | ((unsigned)f2bf(rs * c.w) << 16);
        A.xst[(size_t)f * N_NODES * 4 + n * 4 + off] = o;
    }
    grid.sync();

    // ---------- P4: counting-sort placement (LDS u16 cursors, no global atomics) ----------
    {
        unsigned int* cur = (unsigned int*)lds_raw;
        uint4* c4 = (uint4*)lds_raw;
        for (int i = t; i < NW / 4; i += NTHREADS) c4[i] = make_uint4(0, 0, 0, 0);
        __syncthreads();
        const int2* p = A.el2 + b * EPB;
        const unsigned char* br = A.brel + (size_t)b * N_NODES;
        for (int i = t; i < EPB; i += NTHREADS) {
            int2 st = p[i];
            int n = st.y;
            unsigned old = atomicAdd(&cur[n >> 1], 1u << ((n & 1) * 16));
            int rank = (old >> ((n & 1) * 16)) & 0xFFFF;
            A.srcs[A.row_start[n] + (int)br[n] + rank] = (unsigned short)st.x;
        }
    }
    grid.sync();

    // ---------- P5: gather, pass-major (R6-style direct index loads) ----------
    for (int pass = 0; pass < 4; ++pass) {
        const unsigned short* xb = (const unsigned short*)A.xst + (size_t)pass * N_NODES * 32;
        unsigned short* ub = A.ut + (size_t)pass * N_NODES * 32;
        for (int u = b * NTHREADS + t; u < N_NODES * 8; u += TOTTHREADS) {
            int n = u >> 3, d = u & 7;
            int cnt = A.deg_out[n];
            float rd = rsqrtf((float)(cnt + 1));
            ushort4 sv = *(const ushort4*)&xb[n * 32 + d * 4];  // self (rs-scaled)
            float a0 = bf2f(sv.x), a1 = bf2f(sv.y), a2 = bf2f(sv.z), a3 = bf2f(sv.w);
            const unsigned short* p = A.srcs + A.row_start[n];
            int k = 0;
            for (; k + 8 <= cnt; k += 8) {
                ushort4 v[8];
                #pragma unroll
                for (int j = 0; j < 8; ++j)
                    v[j] = *(const ushort4*)&xb[(int)p[k + j] * 32 + d * 4];
                #pragma unroll
                for (int j = 0; j < 8; ++j) {
                    a0 += bf2f(v[j].x); a1 += bf2f(v[j].y);
                    a2 += bf2f(v[j].z); a3 += bf2f(v[j].w);
                }
            }
            for (; k < cnt; ++k) {
                ushort4 vv = *(const ushort4*)&xb[(int)p[k] * 32 + d * 4];
                a0 += bf2f(vv.x); a1 += bf2f(vv.y); a2 += bf2f(vv.z); a3 += bf2f(vv.w);
            }
            ushort4 o;
            o.x = f2bf(rd * a0); o.y = f2bf(rd * a1);
            o.z = f2bf(rd * a2); o.w = f2bf(rd * a3);
            *(ushort4*)&ub[n * 32 + d * 4] = o;
        }
    }
    grid.sync();

    // ---------- P6: out = relu(u @ W^T + b) via bf16 MFMA; 256 rows/block ----------
    if (b < RB) {
        unsigned short* Wl = (unsigned short*)lds_raw;  // stride 136 bf16
        for (int i = t; i < 128 * 32; i += NTHREADS) {
            int r = i >> 5, c = i & 31;
            float4 w4 = *(const float4*)&A.W[r * D + c * 4];
            ushort4 hh;
            hh.x = f2bf(w4.x); hh.y = f2bf(w4.y); hh.z = f2bf(w4.z); hh.w = f2bf(w4.w);
            *(ushort4*)&Wl[r * 136 + c * 4] = hh;
        }
        __syncthreads();

        const int q4 = t >> 8;          // 64-row sub-tile 0..3
        const int t256 = t & 255;
        const int wv = t256 >> 6;       // 16-row group within sub-tile
        const int lane = t & 63, ml = lane & 15, q = lane >> 4;
        const int base = b * 256 + q4 * 64;
        const int arow = base + wv * 16 + ml;

        short8 a[4];
        if (arow < N_NODES) {
            #pragma unroll
            for (int kt = 0; kt < 4; ++kt)   // k-chunk kt lives in feature tile kt
                a[kt] = *(const short8*)&A.ut[(size_t)kt * N_NODES * 32 + arow * 32 + q * 8];
        } else {
            #pragma unroll
            for (int kt = 0; kt < 4; ++kt) a[kt] = (short8){0, 0, 0, 0, 0, 0, 0, 0};
        }

        f32x4 acc[8];
        #pragma unroll
        for (int jj = 0; jj < 8; ++jj) acc[jj] = (f32x4){0.f, 0.f, 0.f, 0.f};

        #pragma unroll
        for (int jj = 0; jj < 8; ++jj) {
            #pragma unroll
            for (int kt = 0; kt < 4; ++kt) {
                short8 bw = *(const short8*)&Wl[(jj * 16 + ml) * 136 + kt * 32 + q * 8];
                acc[jj] = __builtin_amdgcn_mfma_f32_16x16x32_bf16(a[kt], bw, acc[jj], 0, 0, 0);
            }
        }

        #pragma unroll
        for (int jj = 0; jj < 8; ++jj) {
            float bj = A.bias[jj * 16 + ml];
            #pragma unroll
            for (int r4 = 0; r4 < 4; ++r4) {
                int node = base + wv * 16 + q * 4 + r4;
                if (node < N_NODES) {
                    float v = acc[jj][r4] + bj;
                    A.out[node * D + jj * 16 + ml] = v > 0.f ? v : 0.f;
                }
            }
        }
    }
}

extern "C" void kernel_launch(void* const* d_in, const int* in_sizes, int n_in,
                              void* d_out, int out_size, void* d_ws, size_t ws_size,
                              hipStream_t stream) {
    // workspace layout (4B words); brel aliases ut (disjoint lifetimes:
    // brel written P2 / read P4; ut written P5 / read P6).
    unsigned int* partials = (unsigned int*)d_ws;                           // HP*NW = 6.4M
    unsigned short* xst    = (unsigned short*)(partials + (size_t)HP * NW); // N*128 bf16
    unsigned short* ut     = xst + (size_t)N_NODES * D;                     // N*128 bf16
    unsigned short* srcs   = ut + (size_t)N_NODES * D;                      // E u16
    int* deg_in    = (int*)(srcs + N_EDGES);                                // N
    int* deg_out   = deg_in + N_NODES;                                      // N
    int* row_start = deg_out + N_NODES;                                     // N
    int* blk_sum   = row_start + N_NODES;                                   // RB
    // total ~ 54 MB

    KArgs ha;
    ha.el2       = (const int2*)d_in[0];
    ha.partials  = partials;
    ha.brel      = (unsigned char*)ut;   // alias
    ha.deg_in    = deg_in;
    ha.deg_out   = deg_out;
    ha.blk_sum   = blk_sum;
    ha.row_start = row_start;
    ha.x4        = (const float4*)d_in[1];
    ha.xst       = (uint4*)xst;
    ha.srcs      = srcs;
    ha.W         = (const float*)d_in[2];
    ha.bias      = (const float*)d_in[3];
    ha.ut        = ut;
    ha.out       = (float*)d_out;

    void* kargs[] = { &ha };
    hipLaunchCooperativeKernel((const void*)k_mega, dim3(NBLOCKS), dim3(NTHREADS),
                               kargs, 0, stream);
}

// Round 10
// 203.989 us; speedup vs baseline: 1.8662x; 1.8662x over previous
//
#include <hip/hip_runtime.h>

#define N_NODES 50000
#define N_EDGES 800000
#define D 128
#define HP 128              // histogram / fill partition blocks
#define EPB (N_EDGES / HP)  // 6250 edges per partition
#define NW (N_NODES / 2)    // 25000 packed u32 words (2 nodes/word)
#define NWB 98              // ceil(NW/256) reduce/scan blocks (512 nodes each)

typedef __attribute__((ext_vector_type(8))) short short8;            // 8 bf16 (MFMA frag)
typedef __attribute__((ext_vector_type(8))) unsigned short ushort8;  // 8 u16
typedef __attribute__((ext_vector_type(4))) float f32x4;

__device__ __forceinline__ unsigned short f2bf(float f) {
    unsigned u = __float_as_uint(f);
    return (unsigned short)((u + 0x7FFFu + ((u >> 16) & 1u)) >> 16);  // RNE
}
__device__ __forceinline__ float bf2f(unsigned short h) {
    return __uint_as_float((unsigned)h << 16);
}

// ---- degrees via per-block LDS histograms (no global atomics) ----
// LDS word w packs: in[2w](b0) | out[2w](b1) | in[2w+1](b2) | out[2w+1](b3), u8 each.
__global__ __launch_bounds__(256) void k_hist(const int2* __restrict__ el2,
                                              unsigned int* __restrict__ partials) {
    __shared__ unsigned int h[NW];  // 100 KB
    int t = threadIdx.x;
    for (int i = t; i < NW / 4; i += 256) ((uint4*)h)[i] = make_uint4(0, 0, 0, 0);
    __syncthreads();
    const int2* p = el2 + blockIdx.x * EPB;
    for (int i = t; i < EPB; i += 256) {
        int2 st = p[i];
        atomicAdd(&h[st.x >> 1], 1u << ((st.x & 1) * 16));       // in-degree byte
        atomicAdd(&h[st.y >> 1], 256u << ((st.y & 1) * 16));     // out-degree byte
    }
    __syncthreads();
    uint4* dst = (uint4*)(partials + (size_t)blockIdx.x * NW);
    for (int i = t; i < NW / 4; i += 256) dst[i] = ((uint4*)h)[i];
}

// ---- fused: degree totals + cross-block exclusive prefixes (brel) + 512-node
// block sums. so = sum of (v>>8)&0x00FF00FF -> out[2w] in so[15:0],
// out[2w+1] in so[31:16] (counts <= ~60; high bytes stay 0). ----
__global__ __launch_bounds__(256) void k_reduce(const unsigned int* __restrict__ partials,
                                                unsigned char* __restrict__ brel,
                                                int* __restrict__ deg_in,
                                                int* __restrict__ deg_out,
                                                int* __restrict__ blk_sum) {
    __shared__ int sc[256];
    int t = threadIdx.x;
    int w = blockIdx.x * 256 + t;
    unsigned int si = 0, so = 0;
    if (w < NW) {
        for (int p = 0; p < HP; ++p) {
            unsigned pre = (so & 0xFFu) | (((so >> 16) & 0xFFu) << 8);
            ((unsigned short*)(brel + (size_t)p * N_NODES))[w] = (unsigned short)pre;
            unsigned int v = partials[p * NW + w];
            si += v & 0x00FF00FFu;
            so += (v >> 8) & 0x00FF00FFu;
        }
        *(int2*)&deg_in[2 * w]  = make_int2(si & 0xFFFF, si >> 16);
        *(int2*)&deg_out[2 * w] = make_int2(so & 0xFFFF, so >> 16);
    }
    sc[t] = (w < NW) ? (int)((so & 0xFFFFu) + (so >> 16)) : 0;
    __syncthreads();
    for (int s = 128; s > 0; s >>= 1) {
        if (t < s) sc[t] += sc[t + s];
        __syncthreads();
    }
    if (t == 0) blk_sum[blockIdx.x] = sc[0];
}

// exclusive scan of the NWB block sums (single block)
__global__ void k_scan_b(const int* __restrict__ blk_sum, int* __restrict__ blk_off) {
    __shared__ int sc[256];
    int t = threadIdx.x;
    int v = (t < NWB) ? blk_sum[t] : 0;
    sc[t] = v;
    __syncthreads();
    for (int off = 1; off < 256; off <<= 1) {
        int a = (t >= off) ? sc[t - off] : 0;
        __syncthreads();
        sc[t] += a;
        __syncthreads();
    }
    if (t < NWB) blk_off[t] = sc[t] - v;  // exclusive
}

// row_start over 512 nodes/block (2 per thread)
__global__ void k_scan_c(const int* __restrict__ deg_out, const int* __restrict__ blk_off,
                         int* __restrict__ row_start) {
    __shared__ int sc[256];
    int t = threadIdx.x;
    int w = blockIdx.x * 256 + t;
    int v0 = 0, v1 = 0;
    if (w < NW) { int2 d2 = *(const int2*)&deg_out[2 * w]; v0 = d2.x; v1 = d2.y; }
    int pair = v0 + v1;
    sc[t] = pair;
    __syncthreads();
    for (int off = 1; off < 256; off <<= 1) {
        int a = (t >= off) ? sc[t - off] : 0;
        __syncthreads();
        sc[t] += a;
        __syncthreads();
    }
    if (w < NW) {
        int base = blk_off[blockIdx.x] + sc[t] - pair;
        *(int2*)&row_start[2 * w] = make_int2(base, base + v0);
    }
}

// ---- xs[n] = bf16(rsqrt(deg_in[n]+1) * x[n]), row-major [N][128] ----
__global__ void k_prescale(const float4* __restrict__ x4, const int* __restrict__ deg_in,
                           uint4* __restrict__ xs16) {
    int g = blockIdx.x * blockDim.x + threadIdx.x;  // N*16 groups of 8 elems
    int n = g >> 4;
    float rs = rsqrtf((float)(deg_in[n] + 1));
    float4 a = x4[g * 2], c = x4[g * 2 + 1];
    uint4 o;
    o.x = f2bf(rs * a.x) | ((unsigned)f2bf(rs * a.y) << 16);
    o.y = f2bf(rs * a.z) | ((unsigned)f2bf(rs * a.w) << 16);
    o.z = f2bf(rs * c.x) | ((unsigned)f2bf(rs * c.y) << 16);
    o.w = f2bf(rs * c.z) | ((unsigned)f2bf(rs * c.w) << 16);
    xs16[g] = o;
}

// ---- counting-sort placement, NO global atomics; srcs stored as u16 ----
__global__ __launch_bounds__(256) void k_fill(const int2* __restrict__ el2,
                                              const int* __restrict__ row_start,
                                              const unsigned char* __restrict__ brel,
                                              unsigned short* __restrict__ srcs) {
    __shared__ unsigned int cur[NW];  // 100 KB packed u16 cursors
    int t = threadIdx.x;
    for (int i = t; i < NW / 4; i += 256) ((uint4*)cur)[i] = make_uint4(0, 0, 0, 0);
    __syncthreads();
    const int2* p = el2 + blockIdx.x * EPB;
    const unsigned char* br = brel + (size_t)blockIdx.x * N_NODES;
    for (int i = t; i < EPB; i += 256) {
        int2 st = p[i];
        int n = st.y;
        unsigned old = atomicAdd(&cur[n >> 1], 1u << ((n & 1) * 16));
        int rank = (old >> ((n & 1) * 16)) & 0xFFFF;
        srcs[row_start[n] + (int)br[n] + rank] = (unsigned short)st.x;
    }
}

// ---- fused gather + GEMM: per 64-node tile, gather u rows into LDS (bf16),
// then out = relu(u @ W^T + b) via MFMA. No ut round-trip through HBM.
// Gather: 16 lanes/node x ushort8 (16B) = full 256B row per edge, unroll x4.
__global__ __launch_bounds__(256) void k_gg(const unsigned short* __restrict__ xs,
                                            const unsigned short* __restrict__ srcs,
                                            const int* __restrict__ row_start,
                                            const int* __restrict__ deg_out,
                                            const float* __restrict__ W,
                                            const float* __restrict__ bias,
                                            float* __restrict__ out) {
    __shared__ unsigned short Wl[128 * 136];  // W in bf16, stride 136
    __shared__ unsigned short uS[64 * 136];   // gathered u tile, stride 136
    const int tid = threadIdx.x;
    const int base = blockIdx.x * 64;

    // stage W -> LDS bf16
    for (int i = tid; i < 128 * 32; i += 256) {
        int r = i >> 5, c = i & 31;
        float4 w4 = *(const float4*)&W[r * D + c * 4];
        ushort4 hh;
        hh.x = f2bf(w4.x); hh.y = f2bf(w4.y); hh.z = f2bf(w4.z); hh.w = f2bf(w4.w);
        *(ushort4*)&Wl[r * 136 + c * 4] = hh;
    }

    // gather 64 rows into uS: 4 sweeps x (16 nodes x 16 lanes)
    const int dl  = tid & 15;   // feature lane: 8 bf16 at dl*8
    const int nl0 = tid >> 4;   // node within sweep
    for (int s = 0; s < 4; ++s) {
        int n_loc = s * 16 + nl0;
        int n = base + n_loc;
        float acc[8] = {0.f, 0.f, 0.f, 0.f, 0.f, 0.f, 0.f, 0.f};
        if (n < N_NODES) {
            int cnt = deg_out[n];
            float rd = rsqrtf((float)(cnt + 1));
            ushort8 sv = *(const ushort8*)&xs[n * D + dl * 8];  // self (rs-scaled)
            #pragma unroll
            for (int j = 0; j < 8; ++j) acc[j] = bf2f(sv[j]);
            const unsigned short* p = srcs + row_start[n];
            int k = 0;
            for (; k + 4 <= cnt; k += 4) {
                ushort8 v0 = *(const ushort8*)&xs[(int)p[k]     * D + dl * 8];
                ushort8 v1 = *(const ushort8*)&xs[(int)p[k + 1] * D + dl * 8];
                ushort8 v2 = *(const ushort8*)&xs[(int)p[k + 2] * D + dl * 8];
                ushort8 v3 = *(const ushort8*)&xs[(int)p[k + 3] * D + dl * 8];
                #pragma unroll
                for (int j = 0; j < 8; ++j)
                    acc[j] += bf2f(v0[j]) + bf2f(v1[j]) + bf2f(v2[j]) + bf2f(v3[j]);
            }
            for (; k < cnt; ++k) {
                ushort8 vv = *(const ushort8*)&xs[(int)p[k] * D + dl * 8];
                #pragma unroll
                for (int j = 0; j < 8; ++j) acc[j] += bf2f(vv[j]);
            }
            #pragma unroll
            for (int j = 0; j < 8; ++j) acc[j] *= rd;
        }
        ushort8 o;
        #pragma unroll
        for (int j = 0; j < 8; ++j) o[j] = f2bf(acc[j]);
        *(ushort8*)&uS[n_loc * 136 + dl * 8] = o;
    }
    __syncthreads();

    // GEMM: A-frags from uS, B-frags from Wl (layout verified R2..R8)
    const int wv = tid >> 6, lane = tid & 63, ml = lane & 15, q = lane >> 4;

    short8 a[4];
    #pragma unroll
    for (int kt = 0; kt < 4; ++kt)
        a[kt] = *(const short8*)&uS[(wv * 16 + ml) * 136 + kt * 32 + q * 8];

    f32x4 acc[8];
    #pragma unroll
    for (int jj = 0; jj < 8; ++jj) acc[jj] = (f32x4){0.f, 0.f, 0.f, 0.f};

    #pragma unroll
    for (int jj = 0; jj < 8; ++jj) {
        #pragma unroll
        for (int kt = 0; kt < 4; ++kt) {
            short8 bw = *(const short8*)&Wl[(jj * 16 + ml) * 136 + kt * 32 + q * 8];
            acc[jj] = __builtin_amdgcn_mfma_f32_16x16x32_bf16(a[kt], bw, acc[jj], 0, 0, 0);
        }
    }

    #pragma unroll
    for (int jj = 0; jj < 8; ++jj) {
        float bj = bias[jj * 16 + ml];
        #pragma unroll
        for (int r4 = 0; r4 < 4; ++r4) {
            int node = base + wv * 16 + q * 4 + r4;
            if (node < N_NODES) {
                float v = acc[jj][r4] + bj;
                out[node * D + jj * 16 + ml] = v > 0.f ? v : 0.f;
            }
        }
    }
}

extern "C" void kernel_launch(void* const* d_in, const int* in_sizes, int n_in,
                              void* d_out, int out_size, void* d_ws, size_t ws_size,
                              hipStream_t stream) {
    const int*   el = (const int*)d_in[0];
    const float* x  = (const float*)d_in[1];
    const float* W  = (const float*)d_in[2];
    const float* b  = (const float*)d_in[3];
    float* out = (float*)d_out;

    // workspace layout (4B words); brel aliases the region after xs (disjoint
    // lifetimes: brel written by k_reduce, read by k_fill; nothing else uses it).
    unsigned int* partials = (unsigned int*)d_ws;                           // HP*NW = 3.2M
    unsigned short* xs     = (unsigned short*)(partials + (size_t)HP * NW); // N*128 bf16
    unsigned char* brel    = (unsigned char*)(xs + (size_t)N_NODES * D);    // HP*N u8 = 1.6M words
    unsigned short* srcs   = (unsigned short*)(brel + (size_t)HP * N_NODES);// E u16
    int* deg_in    = (int*)(srcs + N_EDGES);                                // N
    int* deg_out   = deg_in + N_NODES;                                      // N
    int* row_start = deg_out + N_NODES;                                     // N
    int* blk_sum   = row_start + N_NODES;                                   // NWB
    int* blk_off   = blk_sum + 256;                                         // NWB

    k_hist<<<HP, 256, 0, stream>>>((const int2*)el, partials);
    k_reduce<<<NWB, 256, 0, stream>>>(partials, brel, deg_in, deg_out, blk_sum);
    k_scan_b<<<1, 256, 0, stream>>>(blk_sum, blk_off);
    k_scan_c<<<NWB, 256, 0, stream>>>(deg_out, blk_off, row_start);
    k_prescale<<<N_NODES * 16 / 256, 256, 0, stream>>>((const float4*)x, deg_in, (uint4*)xs);
    k_fill<<<HP, 256, 0, stream>>>((const int2*)el, row_start, brel, srcs);
    k_gg<<<(N_NODES + 63) / 64, 256, 0, stream>>>(xs, srcs, row_start, deg_out, W, b, out);
}

// Round 11
// 194.134 us; speedup vs baseline: 1.9610x; 1.0508x over previous
//
#include <hip/hip_runtime.h>

#define N_NODES 50000
#define N_EDGES 800000
#define D 128
#define HP 128              // histogram / fill partition blocks
#define EPB (N_EDGES / HP)  // 6250 edges per partition
#define NW (N_NODES / 2)    // 25000 packed u32 words (2 nodes/word)
#define NWB 98              // ceil(NW/256) reduce/scan blocks (512 nodes each)
#define GNB 1563            // ceil(N_NODES/32) gather blocks per feature pass

typedef __attribute__((ext_vector_type(8))) short short8;   // 8 bf16
typedef __attribute__((ext_vector_type(4))) float f32x4;

__device__ __forceinline__ unsigned short f2bf(float f) {
    unsigned u = __float_as_uint(f);
    return (unsigned short)((u + 0x7FFFu + ((u >> 16) & 1u)) >> 16);  // RNE
}
__device__ __forceinline__ float bf2f(unsigned short h) {
    return __uint_as_float((unsigned)h << 16);
}

// ---- degrees via per-block LDS histograms (no global atomics) ----
// LDS word w packs: in[2w](b0) | out[2w](b1) | in[2w+1](b2) | out[2w+1](b3), u8 each.
__global__ __launch_bounds__(256) void k_hist(const int2* __restrict__ el2,
                                              unsigned int* __restrict__ partials) {
    __shared__ unsigned int h[NW];  // 100 KB
    int t = threadIdx.x;
    for (int i = t; i < NW / 4; i += 256) ((uint4*)h)[i] = make_uint4(0, 0, 0, 0);
    __syncthreads();
    const int2* p = el2 + blockIdx.x * EPB;
    for (int i = t; i < EPB; i += 256) {
        int2 st = p[i];
        atomicAdd(&h[st.x >> 1], 1u << ((st.x & 1) * 16));       // in-degree byte
        atomicAdd(&h[st.y >> 1], 256u << ((st.y & 1) * 16));     // out-degree byte
    }
    __syncthreads();
    uint4* dst = (uint4*)(partials + (size_t)blockIdx.x * NW);
    for (int i = t; i < NW / 4; i += 256) dst[i] = ((uint4*)h)[i];
}

// ---- fused: degree totals + brel prefixes + block sums + PRESCALE ----
// so = sum of (v>>8)&0x00FF00FF -> out[2w] in so[15:0], out[2w+1] in so[31:16].
// This block owns nodes [b*512, b*512+512): after computing deg_in in registers,
// stash rs = rsqrt(deg_in+1) in LDS and write xst tiles for those nodes here
// (kills the separate prescale dispatch + the deg_in global round-trip).
__global__ __launch_bounds__(256) void k_reduce(const unsigned int* __restrict__ partials,
                                                unsigned char* __restrict__ brel,
                                                int* __restrict__ deg_out,
                                                int* __restrict__ blk_sum,
                                                const float4* __restrict__ x4,
                                                uint4* __restrict__ xst) {
    __shared__ int sc[256];
    __shared__ float lds_rs[512];
    int t = threadIdx.x;
    int w = blockIdx.x * 256 + t;
    unsigned int si = 0, so = 0;
    if (w < NW) {
        for (int p = 0; p < HP; ++p) {
            unsigned pre = (so & 0xFFu) | (((so >> 16) & 0xFFu) << 8);
            ((unsigned short*)(brel + (size_t)p * N_NODES))[w] = (unsigned short)pre;
            unsigned int v = partials[p * NW + w];
            si += v & 0x00FF00FFu;
            so += (v >> 8) & 0x00FF00FFu;
        }
        *(int2*)&deg_out[2 * w] = make_int2(so & 0xFFFF, so >> 16);
        lds_rs[2 * t]     = rsqrtf((float)((si & 0xFFFFu) + 1));
        lds_rs[2 * t + 1] = rsqrtf((float)((si >> 16) + 1));
    } else {
        lds_rs[2 * t] = 0.f;
        lds_rs[2 * t + 1] = 0.f;
    }
    sc[t] = (w < NW) ? (int)((so & 0xFFFFu) + (so >> 16)) : 0;
    __syncthreads();
    for (int s = 128; s > 0; s >>= 1) {
        if (t < s) sc[t] += sc[t + s];
        __syncthreads();
    }
    if (t == 0) blk_sum[blockIdx.x] = sc[0];

    // prescale this block's 512 nodes: xst[f][n][32] = bf16(rs[n] * x[n][f*32..+32])
    const int nbase = blockIdx.x * 512;
    for (int i = t; i < 512 * 16; i += 256) {
        int n_loc = i >> 4, part = i & 15;
        int n = nbase + n_loc;
        if (n >= N_NODES) break;  // monotone in i: all later i also out of range
        int f = part >> 2, off = part & 3;
        float rs = lds_rs[n_loc];
        float4 a = x4[n * 32 + part * 2], c = x4[n * 32 + part * 2 + 1];
        uint4 o;
        o.x = f2bf(rs * a.x) | ((unsigned)f2bf(rs * a.y) << 16);
        o.y = f2bf(rs * a.z) | ((unsigned)f2bf(rs * a.w) << 16);
        o.z = f2bf(rs * c.x) | ((unsigned)f2bf(rs * c.y) << 16);
        o.w = f2bf(rs * c.z) | ((unsigned)f2bf(rs * c.w) << 16);
        xst[(size_t)f * N_NODES * 4 + n * 4 + off] = o;  // uint4 units (8 bf16)
    }
}

// ---- row_start: inline exclusive scan of the 98 blk_sums + in-block scan ----
__global__ __launch_bounds__(256) void k_scanrow(const int* __restrict__ deg_out,
                                                 const int* __restrict__ blk_sum,
                                                 int* __restrict__ row_start) {
    __shared__ int sc[256];
    __shared__ int s_pref;
    int t = threadIdx.x;
    sc[t] = (t < (int)blockIdx.x) ? blk_sum[t] : 0;  // blockIdx < NWB=98 <= 256
    __syncthreads();
    for (int s = 128; s > 0; s >>= 1) {
        if (t < s) sc[t] += sc[t + s];
        __syncthreads();
    }
    if (t == 0) s_pref = sc[0];
    __syncthreads();
    int blkoff = s_pref;
    int w = blockIdx.x * 256 + t;
    int v0 = 0, v1 = 0;
    if (w < NW) { int2 d2 = *(const int2*)&deg_out[2 * w]; v0 = d2.x; v1 = d2.y; }
    int pair = v0 + v1;
    __syncthreads();
    sc[t] = pair;
    __syncthreads();
    for (int off = 1; off < 256; off <<= 1) {
        int a = (t >= off) ? sc[t - off] : 0;
        __syncthreads();
        sc[t] += a;
        __syncthreads();
    }
    if (w < NW) {
        int base = blkoff + sc[t] - pair;
        *(int2*)&row_start[2 * w] = make_int2(base, base + v0);
    }
}

// ---- counting-sort placement, NO global atomics; srcs stored as u16 ----
__global__ __launch_bounds__(256) void k_fill(const int2* __restrict__ el2,
                                              const int* __restrict__ row_start,
                                              const unsigned char* __restrict__ brel,
                                              unsigned short* __restrict__ srcs) {
    __shared__ unsigned int cur[NW];  // 100 KB packed u16 cursors
    int t = threadIdx.x;
    for (int i = t; i < NW / 4; i += 256) ((uint4*)cur)[i] = make_uint4(0, 0, 0, 0);
    __syncthreads();
    const int2* p = el2 + blockIdx.x * EPB;
    const unsigned char* br = brel + (size_t)blockIdx.x * N_NODES;
    for (int i = t; i < EPB; i += 256) {
        int2 st = p[i];
        int n = st.y;
        unsigned old = atomicAdd(&cur[n >> 1], 1u << ((n & 1) * 16));
        int rank = (old >> ((n & 1) * 16)) & 0xFFFF;
        srcs[row_start[n] + (int)br[n] + rank] = (unsigned short)st.x;
    }
}

// ---- gather (R6-exact): feature-tiled, 4 passes in ONE dispatch, pass-major;
// 8 lanes/node (ushort4 = 8B -> 64B/edge-chunk = 1 cacheline), unroll x8. ----
__global__ __launch_bounds__(256) void k_gather(const unsigned short* __restrict__ xst,
                                                const unsigned short* __restrict__ srcs,
                                                const int* __restrict__ row_start,
                                                const int* __restrict__ deg_out,
                                                unsigned short* __restrict__ ut) {
    int pass = blockIdx.x / GNB;
    int idx  = blockIdx.x - pass * GNB;
    int n = idx * 32 + (threadIdx.x >> 3);
    if (n >= N_NODES) return;
    int d = threadIdx.x & 7;
    const unsigned short* xb = xst + (size_t)pass * N_NODES * 32;
    int cnt = deg_out[n];
    float rd = rsqrtf((float)(cnt + 1));
    ushort4 sv = *(const ushort4*)&xb[n * 32 + d * 4];  // self (rs-scaled)
    float a0 = bf2f(sv.x), a1 = bf2f(sv.y), a2 = bf2f(sv.z), a3 = bf2f(sv.w);
    const unsigned short* p = srcs + row_start[n];
    int k = 0;
    for (; k + 8 <= cnt; k += 8) {
        ushort4 v[8];
        #pragma unroll
        for (int j = 0; j < 8; ++j)
            v[j] = *(const ushort4*)&xb[(int)p[k + j] * 32 + d * 4];
        #pragma unroll
        for (int j = 0; j < 8; ++j) {
            a0 += bf2f(v[j].x); a1 += bf2f(v[j].y);
            a2 += bf2f(v[j].z); a3 += bf2f(v[j].w);
        }
    }
    for (; k < cnt; ++k) {
        ushort4 vv = *(const ushort4*)&xb[(int)p[k] * 32 + d * 4];
        a0 += bf2f(vv.x); a1 += bf2f(vv.y); a2 += bf2f(vv.z); a3 += bf2f(vv.w);
    }
    ushort4 o;
    o.x = f2bf(rd * a0); o.y = f2bf(rd * a1); o.z = f2bf(rd * a2); o.w = f2bf(rd * a3);
    *(ushort4*)&ut[(size_t)pass * N_NODES * 32 + n * 32 + d * 4] = o;
}

// ---- combine (R6-exact): out = relu(u @ W^T + b) via bf16 MFMA ----
__global__ __launch_bounds__(256) void k_gemm(const float* __restrict__ W,
                                              const float* __restrict__ bias,
                                              const unsigned short* __restrict__ ut,
                                              float* __restrict__ out) {
    __shared__ unsigned short Wl[128 * 136];
    const int tid = threadIdx.x;
    for (int i = tid; i < 128 * 32; i += 256) {
        int r = i >> 5, c = i & 31;
        float4 w4 = *(const float4*)&W[r * D + c * 4];
        ushort4 hh;
        hh.x = f2bf(w4.x); hh.y = f2bf(w4.y); hh.z = f2bf(w4.z); hh.w = f2bf(w4.w);
        *(ushort4*)&Wl[r * 136 + c * 4] = hh;
    }
    __syncthreads();

    const int wv = tid >> 6, lane = tid & 63, ml = lane & 15, q = lane >> 4;
    const int nchunks = (N_NODES + 63) / 64;

    for (int chunk = blockIdx.x; chunk < nchunks; chunk += gridDim.x) {
        int base = chunk * 64;
        int arow = base + wv * 16 + ml;

        short8 a[4];
        if (arow < N_NODES) {
            #pragma unroll
            for (int kt = 0; kt < 4; ++kt)   // k-chunk kt lives in feature tile kt
                a[kt] = *(const short8*)&ut[(size_t)kt * N_NODES * 32 + arow * 32 + q * 8];
        } else {
            #pragma unroll
            for (int kt = 0; kt < 4; ++kt) a[kt] = (short8){0, 0, 0, 0, 0, 0, 0, 0};
        }

        f32x4 acc[8];
        #pragma unroll
        for (int jj = 0; jj < 8; ++jj) acc[jj] = (f32x4){0.f, 0.f, 0.f, 0.f};

        #pragma unroll
        for (int jj = 0; jj < 8; ++jj) {
            #pragma unroll
            for (int kt = 0; kt < 4; ++kt) {
                short8 bw = *(const short8*)&Wl[(jj * 16 + ml) * 136 + kt * 32 + q * 8];
                acc[jj] = __builtin_amdgcn_mfma_f32_16x16x32_bf16(a[kt], bw, acc[jj], 0, 0, 0);
            }
        }

        #pragma unroll
        for (int jj = 0; jj < 8; ++jj) {
            float bj = bias[jj * 16 + ml];
            #pragma unroll
            for (int r4 = 0; r4 < 4; ++r4) {
                int node = base + wv * 16 + q * 4 + r4;
                if (node < N_NODES) {
                    float v = acc[jj][r4] + bj;
                    out[node * D + jj * 16 + ml] = v > 0.f ? v : 0.f;
                }
            }
        }
    }
}

extern "C" void kernel_launch(void* const* d_in, const int* in_sizes, int n_in,
                              void* d_out, int out_size, void* d_ws, size_t ws_size,
                              hipStream_t stream) {
    const int*   el = (const int*)d_in[0];
    const float* x  = (const float*)d_in[1];
    const float* W  = (const float*)d_in[2];
    const float* b  = (const float*)d_in[3];
    float* out = (float*)d_out;

    // workspace layout (4B words); brel aliases ut (disjoint lifetimes:
    // brel written by k_reduce, read by k_fill; ut written by k_gather AFTER fill).
    unsigned int* partials = (unsigned int*)d_ws;                           // HP*NW = 3.2M
    unsigned short* xst    = (unsigned short*)(partials + (size_t)HP * NW); // N*128 bf16
    unsigned short* ut     = xst + (size_t)N_NODES * D;                     // N*128 bf16
    unsigned char* brel    = (unsigned char*)ut;                            // HP*N u8 (alias)
    unsigned short* srcs   = ut + (size_t)N_NODES * D;                      // E u16
    int* deg_out   = (int*)(srcs + N_EDGES);                                // N
    int* row_start = deg_out + N_NODES;                                     // N
    int* blk_sum   = row_start + N_NODES;                                   // NWB
    // total ~ 37 MB

    k_hist<<<HP, 256, 0, stream>>>((const int2*)el, partials);
    k_reduce<<<NWB, 256, 0, stream>>>(partials, brel, deg_out, blk_sum,
                                      (const float4*)x, (uint4*)xst);
    k_scanrow<<<NWB, 256, 0, stream>>>(deg_out, blk_sum, row_start);
    k_fill<<<HP, 256, 0, stream>>>((const int2*)el, row_start, brel, srcs);
    k_gather<<<4 * GNB, 256, 0, stream>>>(xst, srcs, row_start, deg_out, ut);
    k_gemm<<<256, 256, 0, stream>>>(W, b, ut, out);
}

// Round 12
// 192.058 us; speedup vs baseline: 1.9822x; 1.0108x over previous
//
#include <hip/hip_runtime.h>

#define N_NODES 50000
#define N_EDGES 800000
#define D 128
#define HP 128              // histogram / fill partition blocks
#define EPB (N_EDGES / HP)  // 6250 edges per partition
#define NW (N_NODES / 2)    // 25000 packed u32 words (2 nodes/word)
#define NWB 98              // ceil(NW/256) reduce/scan blocks (512 nodes each)
#define GNB 1563            // ceil(N_NODES/32) gather blocks per feature pass

typedef __attribute__((ext_vector_type(8))) short short8;   // 8 bf16
typedef __attribute__((ext_vector_type(4))) float f32x4;

__device__ __forceinline__ unsigned short f2bf(float f) {
    unsigned u = __float_as_uint(f);
    return (unsigned short)((u + 0x7FFFu + ((u >> 16) & 1u)) >> 16);  // RNE
}
__device__ __forceinline__ float bf2f(unsigned short h) {
    return __uint_as_float((unsigned)h << 16);
}

// ---- degrees via per-block LDS histograms (no global atomics) ----
// LDS word w packs: in[2w](b0) | out[2w](b1) | in[2w+1](b2) | out[2w+1](b3), u8 each.
__global__ __launch_bounds__(256) void k_hist(const int2* __restrict__ el2,
                                              unsigned int* __restrict__ partials) {
    __shared__ unsigned int h[NW];  // 100 KB
    int t = threadIdx.x;
    for (int i = t; i < NW / 4; i += 256) ((uint4*)h)[i] = make_uint4(0, 0, 0, 0);
    __syncthreads();
    const int2* p = el2 + blockIdx.x * EPB;
    for (int i = t; i < EPB; i += 256) {
        int2 st = p[i];
        atomicAdd(&h[st.x >> 1], 1u << ((st.x & 1) * 16));       // in-degree byte
        atomicAdd(&h[st.y >> 1], 256u << ((st.y & 1) * 16));     // out-degree byte
    }
    __syncthreads();
    uint4* dst = (uint4*)(partials + (size_t)blockIdx.x * NW);
    for (int i = t; i < NW / 4; i += 256) dst[i] = ((uint4*)h)[i];
}

// ---- fused: degree totals + cross-block exclusive prefixes (brel) + 512-node
// block sums. so = sum of (v>>8)&0x00FF00FF -> out[2w] in so[15:0],
// out[2w+1] in so[31:16] (counts <= ~60; high bytes stay 0). ----
__global__ __launch_bounds__(256) void k_reduce(const unsigned int* __restrict__ partials,
                                                unsigned char* __restrict__ brel,
                                                int* __restrict__ deg_in,
                                                int* __restrict__ deg_out,
                                                int* __restrict__ blk_sum) {
    __shared__ int sc[256];
    int t = threadIdx.x;
    int w = blockIdx.x * 256 + t;
    unsigned int si = 0, so = 0;
    if (w < NW) {
        for (int p = 0; p < HP; ++p) {
            unsigned pre = (so & 0xFFu) | (((so >> 16) & 0xFFu) << 8);
            ((unsigned short*)(brel + (size_t)p * N_NODES))[w] = (unsigned short)pre;
            unsigned int v = partials[p * NW + w];
            si += v & 0x00FF00FFu;
            so += (v >> 8) & 0x00FF00FFu;
        }
        *(int2*)&deg_in[2 * w]  = make_int2(si & 0xFFFF, si >> 16);
        *(int2*)&deg_out[2 * w] = make_int2(so & 0xFFFF, so >> 16);
    }
    sc[t] = (w < NW) ? (int)((so & 0xFFFFu) + (so >> 16)) : 0;
    __syncthreads();
    for (int s = 128; s > 0; s >>= 1) {
        if (t < s) sc[t] += sc[t + s];
        __syncthreads();
    }
    if (t == 0) blk_sum[blockIdx.x] = sc[0];
}

// exclusive scan of the NWB block sums (single block)
__global__ void k_scan_b(const int* __restrict__ blk_sum, int* __restrict__ blk_off) {
    __shared__ int sc[256];
    int t = threadIdx.x;
    int v = (t < NWB) ? blk_sum[t] : 0;
    sc[t] = v;
    __syncthreads();
    for (int off = 1; off < 256; off <<= 1) {
        int a = (t >= off) ? sc[t - off] : 0;
        __syncthreads();
        sc[t] += a;
        __syncthreads();
    }
    if (t < NWB) blk_off[t] = sc[t] - v;  // exclusive
}

// row_start over 512 nodes/block (2 per thread)
__global__ void k_scan_c(const int* __restrict__ deg_out, const int* __restrict__ blk_off,
                         int* __restrict__ row_start) {
    __shared__ int sc[256];
    int t = threadIdx.x;
    int w = blockIdx.x * 256 + t;
    int v0 = 0, v1 = 0;
    if (w < NW) { int2 d2 = *(const int2*)&deg_out[2 * w]; v0 = d2.x; v1 = d2.y; }
    int pair = v0 + v1;
    sc[t] = pair;
    __syncthreads();
    for (int off = 1; off < 256; off <<= 1) {
        int a = (t >= off) ? sc[t - off] : 0;
        __syncthreads();
        sc[t] += a;
        __syncthreads();
    }
    if (w < NW) {
        int base = blk_off[blockIdx.x] + sc[t] - pair;
        *(int2*)&row_start[2 * w] = make_int2(base, base + v0);
    }
}

// ---- counting-sort placement, NO global atomics; srcs stored as u16 ----
__global__ __launch_bounds__(256) void k_fill(const int2* __restrict__ el2,
                                              const int* __restrict__ row_start,
                                              const unsigned char* __restrict__ brel,
                                              unsigned short* __restrict__ srcs) {
    __shared__ unsigned int cur[NW];  // 100 KB packed u16 cursors
    int t = threadIdx.x;
    for (int i = t; i < NW / 4; i += 256) ((uint4*)cur)[i] = make_uint4(0, 0, 0, 0);
    __syncthreads();
    const int2* p = el2 + blockIdx.x * EPB;
    const unsigned char* br = brel + (size_t)blockIdx.x * N_NODES;
    for (int i = t; i < EPB; i += 256) {
        int2 st = p[i];
        int n = st.y;
        unsigned old = atomicAdd(&cur[n >> 1], 1u << ((n & 1) * 16));
        int rank = (old >> ((n & 1) * 16)) & 0xFFFF;
        srcs[row_start[n] + (int)br[n] + rank] = (unsigned short)st.x;
    }
}

// ---- xst[f][n][32] = bf16(rsqrt(deg_in[n]+1) * x[n][f*32..f*32+32]) ----
__global__ void k_prescale(const float4* __restrict__ x4, const int* __restrict__ deg_in,
                           uint4* __restrict__ xst) {
    int g = blockIdx.x * blockDim.x + threadIdx.x;  // N*16 groups of 8 elems
    int n = g >> 4, part = g & 15;
    int f = part >> 2, off = part & 3;
    float rs = rsqrtf((float)(deg_in[n] + 1));
    float4 a = x4[g * 2], c = x4[g * 2 + 1];
    uint4 o;
    o.x = f2bf(rs * a.x) | ((unsigned)f2bf(rs * a.y) << 16);
    o.y = f2bf(rs * a.z) | ((unsigned)f2bf(rs * a.w) << 16);
    o.z = f2bf(rs * c.x) | ((unsigned)f2bf(rs * c.y) << 16);
    o.w = f2bf(rs * c.z) | ((unsigned)f2bf(rs * c.w) << 16);
    xst[(size_t)f * N_NODES * 4 + n * 4 + off] = o;  // uint4 units (8 bf16)
}

// ---- gather, feature-tiled: pass f reads only xst[f] (3.2MB tile);
// 4 passes in ONE dispatch, pass-major. 8 lanes/node (ushort4 = 8B ->
// 64B/edge-chunk = 1 cacheline), unroll x8. ----
__global__ __launch_bounds__(256) void k_gather(const unsigned short* __restrict__ xst,
                                                const unsigned short* __restrict__ srcs,
                                                const int* __restrict__ row_start,
                                                const int* __restrict__ deg_out,
                                                unsigned short* __restrict__ ut) {
    int pass = blockIdx.x / GNB;       // pass-major ordering
    int idx  = blockIdx.x - pass * GNB;
    int n = idx * 32 + (threadIdx.x >> 3);
    if (n >= N_NODES) return;
    int d = threadIdx.x & 7;
    const unsigned short* xb = xst + (size_t)pass * N_NODES * 32;
    int cnt = deg_out[n];
    float rd = rsqrtf((float)(cnt + 1));
    ushort4 sv = *(const ushort4*)&xb[n * 32 + d * 4];  // self (rs-scaled)
    float a0 = bf2f(sv.x), a1 = bf2f(sv.y), a2 = bf2f(sv.z), a3 = bf2f(sv.w);
    const unsigned short* p = srcs + row_start[n];
    int k = 0;
    for (; k + 8 <= cnt; k += 8) {
        ushort4 v[8];
        #pragma unroll
        for (int j = 0; j < 8; ++j)
            v[j] = *(const ushort4*)&xb[(int)p[k + j] * 32 + d * 4];
        #pragma unroll
        for (int j = 0; j < 8; ++j) {
            a0 += bf2f(v[j].x); a1 += bf2f(v[j].y);
            a2 += bf2f(v[j].z); a3 += bf2f(v[j].w);
        }
    }
    for (; k < cnt; ++k) {
        ushort4 vv = *(const ushort4*)&xb[(int)p[k] * 32 + d * 4];
        a0 += bf2f(vv.x); a1 += bf2f(vv.y); a2 += bf2f(vv.z); a3 += bf2f(vv.w);
    }
    ushort4 o;
    o.x = f2bf(rd * a0); o.y = f2bf(rd * a1); o.z = f2bf(rd * a2); o.w = f2bf(rd * a3);
    *(ushort4*)&ut[(size_t)pass * N_NODES * 32 + n * 32 + d * 4] = o;
}

// ---- combine: out = relu(u @ W^T + b) via bf16 MFMA; u is feature-tiled ----
__global__ __launch_bounds__(256) void k_gemm(const float* __restrict__ W,
                                              const float* __restrict__ bias,
                                              const unsigned short* __restrict__ ut,
                                              float* __restrict__ out) {
    __shared__ unsigned short Wl[128 * 136];
    const int tid = threadIdx.x;
    for (int i = tid; i < 128 * 32; i += 256) {
        int r = i >> 5, c = i & 31;
        float4 w4 = *(const float4*)&W[r * D + c * 4];
        ushort4 hh;
        hh.x = f2bf(w4.x); hh.y = f2bf(w4.y); hh.z = f2bf(w4.z); hh.w = f2bf(w4.w);
        *(ushort4*)&Wl[r * 136 + c * 4] = hh;
    }
    __syncthreads();

    const int wv = tid >> 6, lane = tid & 63, ml = lane & 15, q = lane >> 4;
    const int nchunks = (N_NODES + 63) / 64;

    for (int chunk = blockIdx.x; chunk < nchunks; chunk += gridDim.x) {
        int base = chunk * 64;
        int arow = base + wv * 16 + ml;

        short8 a[4];
        if (arow < N_NODES) {
            #pragma unroll
            for (int kt = 0; kt < 4; ++kt)   // k-chunk kt lives in feature tile kt
                a[kt] = *(const short8*)&ut[(size_t)kt * N_NODES * 32 + arow * 32 + q * 8];
        } else {
            #pragma unroll
            for (int kt = 0; kt < 4; ++kt) a[kt] = (short8){0, 0, 0, 0, 0, 0, 0, 0};
        }

        f32x4 acc[8];
        #pragma unroll
        for (int jj = 0; jj < 8; ++jj) acc[jj] = (f32x4){0.f, 0.f, 0.f, 0.f};

        #pragma unroll
        for (int jj = 0; jj < 8; ++jj) {
            #pragma unroll
            for (int kt = 0; kt < 4; ++kt) {
                short8 bw = *(const short8*)&Wl[(jj * 16 + ml) * 136 + kt * 32 + q * 8];
                acc[jj] = __builtin_amdgcn_mfma_f32_16x16x32_bf16(a[kt], bw, acc[jj], 0, 0, 0);
            }
        }

        #pragma unroll
        for (int jj = 0; jj < 8; ++jj) {
            float bj = bias[jj * 16 + ml];
            #pragma unroll
            for (int r4 = 0; r4 < 4; ++r4) {
                int node = base + wv * 16 + q * 4 + r4;
                if (node < N_NODES) {
                    float v = acc[jj][r4] + bj;
                    out[node * D + jj * 16 + ml] = v > 0.f ? v : 0.f;
                }
            }
        }
    }
}

extern "C" void kernel_launch(void* const* d_in, const int* in_sizes, int n_in,
                              void* d_out, int out_size, void* d_ws, size_t ws_size,
                              hipStream_t stream) {
    const int*   el = (const int*)d_in[0];
    const float* x  = (const float*)d_in[1];
    const float* W  = (const float*)d_in[2];
    const float* b  = (const float*)d_in[3];
    float* out = (float*)d_out;

    // workspace layout (4B words); brel aliases ut (disjoint lifetimes:
    // brel written by k_reduce, read by k_fill; ut written by k_gather AFTER fill).
    unsigned int* partials = (unsigned int*)d_ws;                           // HP*NW = 3.2M
    unsigned short* xst    = (unsigned short*)(partials + (size_t)HP * NW); // N*128 bf16
    unsigned short* ut     = xst + (size_t)N_NODES * D;                     // N*128 bf16
    unsigned char* brel    = (unsigned char*)ut;                            // HP*N u8 (alias)
    unsigned short* srcs   = ut + (size_t)N_NODES * D;                      // E u16
    int* deg_in    = (int*)(srcs + N_EDGES);                                // N
    int* deg_out   = deg_in + N_NODES;                                      // N
    int* row_start = deg_out + N_NODES;                                     // N
    int* blk_sum   = row_start + N_NODES;                                   // NWB
    int* blk_off   = blk_sum + 256;                                         // NWB
    // total ~ 40 MB

    k_hist<<<HP, 256, 0, stream>>>((const int2*)el, partials);
    k_reduce<<<NWB, 256, 0, stream>>>(partials, brel, deg_in, deg_out, blk_sum);
    k_scan_b<<<1, 256, 0, stream>>>(blk_sum, blk_off);
    k_scan_c<<<NWB, 256, 0, stream>>>(deg_out, blk_off, row_start);
    k_prescale<<<N_NODES * 16 / 256, 256, 0, stream>>>((const float4*)x, deg_in, (uint4*)xst);
    k_fill<<<HP, 256, 0, stream>>>((const int2*)el, row_start, brel, srcs);
    k_gather<<<4 * GNB, 256, 0, stream>>>(xst, srcs, row_start, deg_out, ut);
    k_gemm<<<256, 256, 0, stream>>>(W, b, ut, out);
}